// Round 8
// baseline (563.111 us; speedup 1.0000x reference)
//
#include <hip/hip_runtime.h>
#include <hip/hip_bf16.h>
#include <math.h>

typedef __attribute__((ext_vector_type(8))) short bf16x8;
typedef __attribute__((ext_vector_type(8))) unsigned short u16x8;
typedef __attribute__((ext_vector_type(4))) float f32x4;
typedef __attribute__((ext_vector_type(4))) unsigned short u16x4;

__device__ inline unsigned short f2bf(float f) {
    union { float f; unsigned u; } v; v.f = f;
    unsigned r = (v.u + 0x7fff + ((v.u >> 16) & 1)) >> 16;   // RNE
    return (unsigned short)r;
}
__device__ inline float bf2f(unsigned short u) {
    union { unsigned u; float f; } v; v.u = ((unsigned)u) << 16; return v.f;
}

#define GLL16(gp, lp) __builtin_amdgcn_global_load_lds(                      \
    (const __attribute__((address_space(1))) void*)(gp),                     \
    (__attribute__((address_space(3))) void*)(lp), 16, 0, 0)

// ---------------------------------------------------------------------------
// bf16 MFMA GEMM, 256x256 tile, BK=64, 8 waves (2x4), per-wave 128x64 =
// 8x4 frags of 16x16x32. 2-phase syncthreads loop (m248 2ph ref: 655-666 TF
// @K=1024). 64KB single-buffered LDS; rows 128B; stage source cs = c^(r&7),
// read slot (kk*4+lg)^(row&7) (involution, rule 21) -> conflict-free (r7).
// EPI: 0=none 1=+bias 2=+bias+gelu(exact). OUT_BF: bf16 output.
// ---------------------------------------------------------------------------
template<int EPI, int OUT_BF>
__global__ __launch_bounds__(512) void gemm256(
    const unsigned short* __restrict__ A,
    const unsigned short* __restrict__ Bt,
    const float* __restrict__ bias,
    void* __restrict__ Cout,
    int M, int Nn, int K, int ldc)
{
    __shared__ unsigned char lds[65536];        // A 32KB ++ B 32KB
    const int tid = threadIdx.x;
    const int w = tid >> 6, lane = tid & 63;
    const int lk = lane & 15, lg = lane >> 4;
    const int wr = w >> 2, wc = w & 3;          // 2 x 4 wave grid
    const int nbn = Nn >> 8;
    const int nb = gridDim.x;
    int bid = blockIdx.x;
    int swz = (nb & 7) ? bid : (bid & 7) * (nb >> 3) + (bid >> 3);  // XCD swizzle
    const int bm = (swz / nbn) << 8, bn = (swz % nbn) << 8;

    f32x4 acc[8][4] = {};

    for (int k0 = 0; k0 < K; k0 += 64) {
        #pragma unroll
        for (int i = 0; i < 8; ++i) {           // 4096 slots of 16B
            int s = tid + i * 512;
            int r = s >> 3, c = s & 7;
            int cs = c ^ (r & 7);
            const unsigned short* gp = (r < 256)
                ? A  + (size_t)(bm + r) * K + k0 + cs * 8
                : Bt + (size_t)(bn + (r - 256)) * K + k0 + cs * 8;
            GLL16(gp, &lds[s * 16]);
        }
        __syncthreads();                        // compiler drains vmcnt

        #pragma unroll
        for (int kk = 0; kk < 2; ++kk) {
            bf16x8 af[8], bfr[4];
            #pragma unroll
            for (int mi = 0; mi < 8; ++mi) {
                int row = wr * 128 + mi * 16 + lk;
                af[mi] = *(const bf16x8*)&lds[row * 128 + (((kk * 4 + lg) ^ (row & 7)) << 4)];
            }
            #pragma unroll
            for (int nj = 0; nj < 4; ++nj) {
                int row = wc * 64 + nj * 16 + lk;
                bfr[nj] = *(const bf16x8*)&lds[32768 + row * 128 + (((kk * 4 + lg) ^ (row & 7)) << 4)];
            }
            #pragma unroll
            for (int mi = 0; mi < 8; ++mi)
                #pragma unroll
                for (int nj = 0; nj < 4; ++nj)
                    acc[mi][nj] = __builtin_amdgcn_mfma_f32_16x16x32_bf16(af[mi], bfr[nj], acc[mi][nj], 0, 0, 0);
        }
        __syncthreads();
    }

    #pragma unroll
    for (int mi = 0; mi < 8; ++mi) {
        int row = bm + wr * 128 + mi * 16 + lg * 4;
        #pragma unroll
        for (int nj = 0; nj < 4; ++nj) {
            int col = bn + wc * 64 + nj * 16 + lk;
            #pragma unroll
            for (int r = 0; r < 4; ++r) {
                float v = acc[mi][nj][r];
                if (EPI >= 1) v += bias[col];
                if (EPI == 2) v = 0.5f * v * (1.0f + erff(v * 0.7071067811865475f));
                if (OUT_BF)
                    ((unsigned short*)Cout)[(size_t)(row + r) * ldc + col] = f2bf(v);
                else
                    ((float*)Cout)[(size_t)(row + r) * ldc + col] = v;
            }
        }
    }
}

// ---------------------------------------------------------------------------
// bf16 MFMA GEMM, m97 structure + BK=64 + XOR swizzle (round-7 verified):
// 128x128 tile, 4 waves (2x2), single-buffered 32KB LDS, ~5 blocks/CU.
// ---------------------------------------------------------------------------
template<int EPI, int OUT_BF>
__global__ __launch_bounds__(256) void gemm97(
    const unsigned short* __restrict__ A,
    const unsigned short* __restrict__ Bt,
    const float* __restrict__ bias,
    void* __restrict__ Cout,
    int M, int Nn, int K, int ldc)
{
    __shared__ unsigned char lds[32768];        // A 16KB ++ B 16KB
    const int tid = threadIdx.x;
    const int w = tid >> 6, lane = tid & 63;
    const int lk = lane & 15, lg = lane >> 4;
    const int wr = w >> 1, wc = w & 1;
    const int nbn = Nn >> 7;
    const int nb = gridDim.x;
    int bid = blockIdx.x;
    int swz = (nb & 7) ? bid : (bid & 7) * (nb >> 3) + (bid >> 3);  // XCD swizzle
    const int bm = (swz / nbn) << 7, bn = (swz % nbn) << 7;

    f32x4 acc[4][4] = {};

    for (int k0 = 0; k0 < K; k0 += 64) {
        #pragma unroll
        for (int i = 0; i < 8; ++i) {           // 2048 slots of 16B
            int s = tid + i * 256;
            int r = s >> 3, c = s & 7;
            int cs = c ^ (r & 7);
            const unsigned short* gp = (r < 128)
                ? A  + (size_t)(bm + r) * K + k0 + cs * 8
                : Bt + (size_t)(bn + (r - 128)) * K + k0 + cs * 8;
            GLL16(gp, &lds[s * 16]);
        }
        __syncthreads();                        // compiler drains vmcnt

        #pragma unroll
        for (int kk = 0; kk < 2; ++kk) {
            bf16x8 af[4], bfr[4];
            #pragma unroll
            for (int m = 0; m < 4; ++m) {
                int row = wr * 64 + m * 16 + lk;
                af[m] = *(const bf16x8*)&lds[row * 128 + (((kk * 4 + lg) ^ (row & 7)) << 4)];
            }
            #pragma unroll
            for (int n = 0; n < 4; ++n) {
                int row = wc * 64 + n * 16 + lk;
                bfr[n] = *(const bf16x8*)&lds[16384 + row * 128 + (((kk * 4 + lg) ^ (row & 7)) << 4)];
            }
            #pragma unroll
            for (int m = 0; m < 4; ++m)
                #pragma unroll
                for (int n = 0; n < 4; ++n)
                    acc[m][n] = __builtin_amdgcn_mfma_f32_16x16x32_bf16(af[m], bfr[n], acc[m][n], 0, 0, 0);
        }
        __syncthreads();
    }

    #pragma unroll
    for (int m = 0; m < 4; ++m) {
        int row = bm + wr * 64 + m * 16 + lg * 4;
        #pragma unroll
        for (int n = 0; n < 4; ++n) {
            int col = bn + wc * 64 + n * 16 + lk;
            #pragma unroll
            for (int r = 0; r < 4; ++r) {
                float v = acc[m][n][r];
                if (EPI >= 1) v += bias[col];
                if (EPI == 2) v = 0.5f * v * (1.0f + erff(v * 0.7071067811865475f));
                if (OUT_BF)
                    ((unsigned short*)Cout)[(size_t)(row + r) * ldc + col] = f2bf(v);
                else
                    ((float*)Cout)[(size_t)(row + r) * ldc + col] = v;
            }
        }
    }
}

// ---------------------------------------------------------------------------
// fp32 -> bf16 flat convert, 4 elems/thread
// ---------------------------------------------------------------------------
__global__ __launch_bounds__(256) void cvt_bf16(
    const float* __restrict__ src, unsigned short* __restrict__ dst, int n)
{
    int i = (blockIdx.x * 256 + threadIdx.x) * 4;
    if (i < n) {
        float4 v = *(const float4*)(src + i);
        u16x4 o = { f2bf(v.x), f2bf(v.y), f2bf(v.z), f2bf(v.w) };
        *(u16x4*)(dst + i) = o;
    }
}

// ---------------------------------------------------------------------------
// transpose + convert: src [R][Cc] f32 -> dst [Cc][R] bf16 (for B^T weights)
// ---------------------------------------------------------------------------
__global__ __launch_bounds__(256) void transpose_cvt(
    const float* __restrict__ src, unsigned short* __restrict__ dst, int R, int Cc)
{
    __shared__ float t[32][33];
    const int bc = blockIdx.x * 32, br = blockIdx.y * 32;
    const int tx = threadIdx.x & 31, ty = threadIdx.x >> 5;
    #pragma unroll
    for (int i = 0; i < 4; ++i)
        t[ty + i * 8][tx] = src[(size_t)(br + ty + i * 8) * Cc + bc + tx];
    __syncthreads();
    #pragma unroll
    for (int i = 0; i < 4; ++i)
        dst[(size_t)(bc + ty + i * 8) * R + br + tx] = f2bf(t[tx][ty + i * 8]);
}

// ---------------------------------------------------------------------------
// drofe on bf16 QK [M][2048] -> rotated bf16 Q [M][1024] (scale folded), K.
// ---------------------------------------------------------------------------
__global__ __launch_bounds__(256) void drofe_bf(
    const unsigned short* __restrict__ QK, unsigned short* __restrict__ Qo,
    unsigned short* __restrict__ Ko,
    const float* __restrict__ freqband, const float* __restrict__ demo, int N)
{
    const float PI_F = 3.14159265358979323846f;
    int idx = blockIdx.x * 256 + threadIdx.x;
    int col2 = idx & 511;
    int row  = idx >> 9;
    int n = row & (N - 1), b = row >> 10;
    int i  = col2 & 31;
    int ii = (i < 16) ? i : i - 16;
    float fb = (i < 16) ? freqband[n * 2 + 0] : freqband[n * 2 + 1];
    float freq = (1.0f + (float)ii * (4.0f / 15.0f)) * PI_F;
    float ang = fb * freq;
    float cv = cosf(ang), sv = sinf(ang);
    float ca = cv * demo[b * 2 + 0];
    float sg = sv * demo[b * 2 + 1];
    const unsigned* qk = (const unsigned*)(QK + (size_t)row * 2048);
    unsigned qu = qk[col2], ku = qk[512 + col2];
    float qe = bf2f((unsigned short)qu), qo_ = bf2f((unsigned short)(qu >> 16));
    float ke = bf2f((unsigned short)ku), ko_ = bf2f((unsigned short)(ku >> 16));
    const float s8 = 0.125f;
    unsigned qres = (unsigned)f2bf((qe * ca - qo_ * sg) * s8)
                  | ((unsigned)f2bf((qo_ * ca + qe * sg) * s8) << 16);
    unsigned kres = (unsigned)f2bf(ke * ca - ko_ * sg)
                  | ((unsigned)f2bf(ko_ * ca + ke * sg) << 16);
    ((unsigned*)Qo)[(size_t)row * 512 + col2] = qres;
    ((unsigned*)Ko)[(size_t)row * 512 + col2] = kres;
}

// ---------------------------------------------------------------------------
// Flash attention, bf16 in/out, MFMA 16x16x32, fp32 accum. (round-4 verified)
// ---------------------------------------------------------------------------
__global__ __launch_bounds__(256) void attn_mfma(
    const unsigned short* __restrict__ Q, const unsigned short* __restrict__ K,
    const unsigned short* __restrict__ V, unsigned short* __restrict__ O,
    int B, int H, int N)
{
    __shared__ unsigned short Ks[64 * 64];
    __shared__ unsigned short Vt[64 * 72];
    __shared__ unsigned short Ps[4][16 * 72];

    const int bi = blockIdx.x;
    const int bh = (bi & 7) + 8 * ((bi >> 3) & 15);
    const int q0 = (bi >> 7) * 64;
    const int b = bh >> 4, h = bh & 15;
    const int tid = threadIdx.x;
    const int w = tid >> 6, lane = tid & 63;
    const int lg = lane >> 4, lk = lane & 15;

    bf16x8 qf[2];
    {
        const unsigned short* qrow = Q + (size_t)(b * N + q0 + w * 16 + lk) * 1024 + h * 64;
        qf[0] = *(const bf16x8*)(qrow + lg * 8);
        qf[1] = *(const bf16x8*)(qrow + 32 + lg * 8);
    }

    f32x4 o[4] = {};
    float mrow[4], lrow[4];
    #pragma unroll
    for (int r = 0; r < 4; ++r) { mrow[r] = -INFINITY; lrow[r] = 0.f; }

    for (int t0 = 0; t0 < N; t0 += 64) {
        const size_t kvbase = (size_t)(b * N + t0) * 1024 + h * 64;
        #pragma unroll
        for (int it = 0; it < 2; ++it) {
            int s = it * 256 + tid;
            int row = s >> 3, cb = (s & 7) << 4;
            int dby = cb ^ ((row & 7) << 4);
            GLL16(K + kvbase + (size_t)row * 1024 + (dby >> 1), &Ks[s * 8]);
        }
        {
            int c = tid >> 5, k0 = (tid & 31) * 2;
            const unsigned short* vp = V + kvbase + (size_t)k0 * 1024 + c * 8;
            u16x8 va = *(const u16x8*)vp;
            u16x8 vb = *(const u16x8*)(vp + 1024);
            #pragma unroll
            for (int j = 0; j < 8; ++j) {
                unsigned val = (unsigned)va[j] | ((unsigned)vb[j] << 16);
                *(unsigned*)&Vt[(c * 8 + j) * 72 + k0] = val;
            }
        }
        __syncthreads();

        f32x4 s4[4];
        #pragma unroll
        for (int sub = 0; sub < 4; ++sub) {
            f32x4 acc = {0.f, 0.f, 0.f, 0.f};
            #pragma unroll
            for (int kh = 0; kh < 2; ++kh) {
                int cc = (kh * 64 + lg * 16) ^ ((lk & 7) << 4);
                bf16x8 kf = *(const bf16x8*)&Ks[(sub * 16 + lk) * 64 + (cc >> 1)];
                acc = __builtin_amdgcn_mfma_f32_16x16x32_bf16(qf[kh], kf, acc, 0, 0, 0);
            }
            s4[sub] = acc;
        }

        #pragma unroll
        for (int r = 0; r < 4; ++r) {
            float tm = fmaxf(fmaxf(s4[0][r], s4[1][r]), fmaxf(s4[2][r], s4[3][r]));
            #pragma unroll
            for (int msk = 1; msk < 16; msk <<= 1) tm = fmaxf(tm, __shfl_xor(tm, msk));
            float mn = fmaxf(mrow[r], tm);
            float corr = __expf(mrow[r] - mn);
            mrow[r] = mn;
            float psum = 0.f;
            unsigned short pb[4];
            #pragma unroll
            for (int sub = 0; sub < 4; ++sub) {
                float p = __expf(s4[sub][r] - mn);
                psum += p;
                pb[sub] = f2bf(p);
            }
            #pragma unroll
            for (int msk = 1; msk < 16; msk <<= 1) psum += __shfl_xor(psum, msk);
            lrow[r] = lrow[r] * corr + psum;
            #pragma unroll
            for (int ds = 0; ds < 4; ++ds) o[ds][r] *= corr;
            int q = lg * 4 + r;
            #pragma unroll
            for (int sub = 0; sub < 4; ++sub)
                Ps[w][q * 72 + sub * 16 + lk] = pb[sub];
        }
        asm volatile("s_waitcnt lgkmcnt(0)" ::: "memory");

        #pragma unroll
        for (int kh = 0; kh < 2; ++kh) {
            bf16x8 pf = *(const bf16x8*)&Ps[w][lk * 72 + kh * 32 + lg * 8];
            #pragma unroll
            for (int ds = 0; ds < 4; ++ds) {
                bf16x8 vf = *(const bf16x8*)&Vt[(ds * 16 + lk) * 72 + kh * 32 + lg * 8];
                o[ds] = __builtin_amdgcn_mfma_f32_16x16x32_bf16(pf, vf, o[ds], 0, 0, 0);
            }
        }
        __syncthreads();
    }

    #pragma unroll
    for (int ds = 0; ds < 4; ++ds)
        #pragma unroll
        for (int r = 0; r < 4; ++r) {
            int q = lg * 4 + r;
            O[(size_t)(b * N + q0 + w * 16 + q) * 1024 + h * 64 + ds * 16 + lk] =
                f2bf(o[ds][r] / lrow[r]);
        }
}

// ---------------------------------------------------------------------------
// Fused residual + LayerNorm: out = LN(x + gamma*y) * w + b  (+ optional bf16)
// ---------------------------------------------------------------------------
__global__ __launch_bounds__(256) void ln_res_kernel(
    const float* __restrict__ x, const float* __restrict__ y,
    const float* __restrict__ gamma, const float* __restrict__ w,
    const float* __restrict__ bia, float* __restrict__ out,
    unsigned short* __restrict__ out_bf, int C)
{
    const int row = blockIdx.x;
    __shared__ float buf[1024];
    __shared__ float red[8];
    const size_t base = (size_t)row * C;
    float s = 0.f, ss = 0.f;
    for (int c = threadIdx.x; c < C; c += 256) {
        float v = x[base + c] + gamma[c] * y[base + c];
        buf[c] = v; s += v; ss += v * v;
    }
    #pragma unroll
    for (int msk = 1; msk < 64; msk <<= 1) { s += __shfl_xor(s, msk); ss += __shfl_xor(ss, msk); }
    int wv = threadIdx.x >> 6, lane = threadIdx.x & 63;
    if (lane == 0) { red[wv * 2] = s; red[wv * 2 + 1] = ss; }
    __syncthreads();
    if (threadIdx.x == 0) {
        float S = 0.f, SS = 0.f;
        #pragma unroll
        for (int i = 0; i < 4; ++i) { S += red[2 * i]; SS += red[2 * i + 1]; }
        red[0] = S; red[1] = SS;
    }
    __syncthreads();
    float mu = red[0] / C;
    float var = red[1] / C - mu * mu;
    float rstd = rsqrtf(var + 1e-5f);
    for (int c = threadIdx.x; c < C; c += 256) {
        float v = (buf[c] - mu) * rstd * w[c] + bia[c];
        out[base + c] = v;
        if (out_bf) out_bf[base + c] = f2bf(v);
    }
}

// ---------------------------------------------------------------------------
extern "C" void kernel_launch(void* const* d_in, const int* in_sizes, int n_in,
                              void* d_out, int out_size, void* d_ws, size_t ws_size,
                              hipStream_t stream)
{
    const float* x      = (const float*)d_in[0];
    const float* demo   = (const float*)d_in[1];
    const float* expl   = (const float*)d_in[2];
    const float* fb     = (const float*)d_in[3];
    const float* w_qkv  = (const float*)d_in[4];
    const float* w_proj = (const float*)d_in[5];
    const float* b_proj = (const float*)d_in[6];
    const float* gamma1 = (const float*)d_in[7];
    const float* gamma2 = (const float*)d_in[8];
    const float* ln1_w  = (const float*)d_in[9];
    const float* ln1_b  = (const float*)d_in[10];
    const float* ln2_w  = (const float*)d_in[11];
    const float* ln2_b  = (const float*)d_in[12];
    const float* w1     = (const float*)d_in[13];
    const float* b1     = (const float*)d_in[14];
    const float* w2     = (const float*)d_in[15];
    const float* b2     = (const float*)d_in[16];
    float* out = (float*)d_out;

    const int B = 8, N = 1024, C = 1024, F = 4096, H = 16;
    const int M = B * N;                        // 8192
    const size_t Mi = 1048576;

    float* ws = (float*)d_ws;
    unsigned short* QKbf = (unsigned short*)ws;              // M x 2048 bf16
    unsigned short* Obf  = (unsigned short*)ws;              // M x 1024 bf16
    float*          H2   = ws;                               // M x 1024 f32
    unsigned short* Qbf  = (unsigned short*)(ws + 8 * Mi);   // M x 1024 bf16
    unsigned short* Kbf  = (unsigned short*)(ws + 12 * Mi);
    unsigned short* Vbf  = (unsigned short*)(ws + 16 * Mi);
    unsigned short* Hid  = (unsigned short*)(ws + 8 * Mi);   // M x 4096 bf16
    unsigned short* Ebf  = (unsigned short*)(ws + 24 * Mi);
    unsigned short* Xbf  = (unsigned short*)(ws + 28 * Mi);
    float*          Pb   = ws + 24 * Mi;                     // M x 1024 f32
    float*          X1   = ws + 32 * Mi;                     // M x 1024 f32
    unsigned short* X1bf = (unsigned short*)(ws + 40 * Mi);
    unsigned short* Wt   = (unsigned short*)(ws + 44 * Mi);
    unsigned short* wqkvT  = Wt;                             // [3072][1024]
    unsigned short* wprojT = Wt + (size_t)3145728;           // [1024][1024]
    unsigned short* w1T    = wprojT + (size_t)1048576;       // [4096][1024]
    unsigned short* w2T    = w1T + (size_t)4194304;          // [1024][4096]

    dim3 blk(256);
    dim3 blk5(512);
    const int MC = M * C;

    hipLaunchKernelGGL(cvt_bf16, dim3(MC / 1024), blk, 0, stream, expl, Ebf, MC);
    hipLaunchKernelGGL(cvt_bf16, dim3(MC / 1024), blk, 0, stream, x, Xbf, MC);
    hipLaunchKernelGGL(transpose_cvt, dim3(96, 32), blk, 0, stream, w_qkv, wqkvT, C, 3 * C);
    hipLaunchKernelGGL(transpose_cvt, dim3(32, 32), blk, 0, stream, w_proj, wprojT, C, C);
    hipLaunchKernelGGL(transpose_cvt, dim3(128, 32), blk, 0, stream, w1, w1T, C, F);
    hipLaunchKernelGGL(transpose_cvt, dim3(32, 128), blk, 0, stream, w2, w2T, F, C);

    // QK projection (explanation) -> bf16 [256^2 tile]; V projection (x) -> bf16
    hipLaunchKernelGGL((gemm256<0,1>), dim3(32 * 8), blk5, 0, stream, Ebf, wqkvT, (const float*)nullptr, (void*)QKbf, M, 2048, C, 2048);
    hipLaunchKernelGGL((gemm97<0,1>), dim3(64 * 8), blk, 0, stream, Xbf, wqkvT + (size_t)2048 * 1024, (const float*)nullptr, (void*)Vbf, M, 1024, C, 1024);

    // drofe: bf16 QK -> rotated bf16 Q (scaled), K
    hipLaunchKernelGGL(drofe_bf, dim3(M * 512 / 256), blk, 0, stream, QKbf, Qbf, Kbf, fb, demo, N);

    // attention -> bf16 O
    hipLaunchKernelGGL(attn_mfma, dim3(B * H * (N / 64)), blk, 0, stream, Qbf, Kbf, Vbf, Obf, B, H, N);

    // output projection
    hipLaunchKernelGGL((gemm97<1,0>), dim3(64 * 8), blk, 0, stream, Obf, wprojT, b_proj, (void*)Pb, M, 1024, C, 1024);

    // residual + LN1 (f32 + bf16)
    hipLaunchKernelGGL(ln_res_kernel, dim3(M), blk, 0, stream, x, Pb, gamma1, ln1_w, ln1_b, X1, X1bf, C);

    // MLP
    hipLaunchKernelGGL((gemm256<2,1>), dim3(32 * 16), blk5, 0, stream, X1bf, w1T, b1, (void*)Hid, M, F, C, F);
    hipLaunchKernelGGL((gemm97<1,0>), dim3(64 * 8), blk, 0, stream, Hid, w2T, b2, (void*)H2, M, 1024, F, 1024);

    // residual + LN2 -> out
    hipLaunchKernelGGL(ln_res_kernel, dim3(M), blk, 0, stream, X1, H2, gamma2, ln2_w, ln2_b, out, (unsigned short*)nullptr, C);
}

// Round 9
// 508.671 us; speedup vs baseline: 1.1070x; 1.1070x over previous
//
#include <hip/hip_runtime.h>
#include <hip/hip_bf16.h>
#include <math.h>

typedef __attribute__((ext_vector_type(8))) short bf16x8;
typedef __attribute__((ext_vector_type(8))) unsigned short u16x8;
typedef __attribute__((ext_vector_type(4))) float f32x4;
typedef __attribute__((ext_vector_type(4))) unsigned short u16x4;

__device__ inline unsigned short f2bf(float f) {
    union { float f; unsigned u; } v; v.f = f;
    unsigned r = (v.u + 0x7fff + ((v.u >> 16) & 1)) >> 16;   // RNE
    return (unsigned short)r;
}
__device__ inline float bf2f(unsigned short u) {
    union { unsigned u; float f; } v; v.u = ((unsigned)u) << 16; return v.f;
}

#define GLL16(gp, lp) __builtin_amdgcn_global_load_lds(                      \
    (const __attribute__((address_space(1))) void*)(gp),                     \
    (__attribute__((address_space(3))) void*)(lp), 16, 0, 0)

// ---------------------------------------------------------------------------
// bf16 MFMA GEMM, m97 structure, templated BK (r7-verified at BK=64):
// 128x128 tile, 4 waves (2x2), per-wave 64x64 = 4x4 frags of 16x16x32.
// Single-buffered LDS: BK=32 -> 16KB (~6-8 blocks/CU), BK=64 -> 32KB (~5).
// Barrier drain covered by resident-block overlap (m114) — measured r5/r6/r8:
// in-kernel pipelining that cuts blocks/CU loses; occupancy wins.
// LDS rows BK*2 bytes = SPR 16B slots; stage source cs = c^(r&(SPR-1)),
// read slot (kk*4+lg)^(row&(SPR-1)) (involution, rule 21) -> <=2-way (free).
// EPI: 0=none 1=+bias 2=+bias+gelu(tanh-approx, sigmoid form).
// ---------------------------------------------------------------------------
template<int EPI, int OUT_BF, int BK>
__global__ __launch_bounds__(256) void gemm97(
    const unsigned short* __restrict__ A,
    const unsigned short* __restrict__ Bt,
    const float* __restrict__ bias,
    void* __restrict__ Cout,
    int M, int Nn, int K, int ldc)
{
    constexpr int SPR = BK / 8;                 // 16B slots per row (4 or 8)
    constexpr int RB  = BK * 2;                 // row bytes
    __shared__ unsigned char lds[256 * BK * 2]; // A 128 rows ++ B 128 rows
    const int tid = threadIdx.x;
    const int w = tid >> 6, lane = tid & 63;
    const int lk = lane & 15, lg = lane >> 4;
    const int wr = w >> 1, wc = w & 1;
    const int nbn = Nn >> 7;
    const int nb = gridDim.x;
    int bid = blockIdx.x;
    int swz = (nb & 7) ? bid : (bid & 7) * (nb >> 3) + (bid >> 3);  // XCD swizzle
    const int bm = (swz / nbn) << 7, bn = (swz % nbn) << 7;

    f32x4 acc[4][4] = {};

    for (int k0 = 0; k0 < K; k0 += BK) {
        #pragma unroll
        for (int i = 0; i < SPR; ++i) {         // 256*SPR slots of 16B
            int s = tid + i * 256;
            int r = s / SPR, c = s % SPR;
            int cs = c ^ (r & (SPR - 1));
            const unsigned short* gp = (r < 128)
                ? A  + (size_t)(bm + r) * K + k0 + cs * 8
                : Bt + (size_t)(bn + (r - 128)) * K + k0 + cs * 8;
            GLL16(gp, &lds[s * 16]);
        }
        __syncthreads();                        // compiler drains vmcnt

        #pragma unroll
        for (int kk = 0; kk < BK / 32; ++kk) {
            bf16x8 af[4], bfr[4];
            #pragma unroll
            for (int m = 0; m < 4; ++m) {
                int row = wr * 64 + m * 16 + lk;
                int sl = (kk * 4 + lg) ^ (row & (SPR - 1));
                af[m] = *(const bf16x8*)&lds[row * RB + sl * 16];
            }
            #pragma unroll
            for (int n = 0; n < 4; ++n) {
                int row = wc * 64 + n * 16 + lk;
                int sl = (kk * 4 + lg) ^ (row & (SPR - 1));
                bfr[n] = *(const bf16x8*)&lds[128 * RB + row * RB + sl * 16];
            }
            #pragma unroll
            for (int m = 0; m < 4; ++m)
                #pragma unroll
                for (int n = 0; n < 4; ++n)
                    acc[m][n] = __builtin_amdgcn_mfma_f32_16x16x32_bf16(af[m], bfr[n], acc[m][n], 0, 0, 0);
        }
        __syncthreads();
    }

    #pragma unroll
    for (int m = 0; m < 4; ++m) {
        int row = bm + wr * 64 + m * 16 + lg * 4;
        #pragma unroll
        for (int n = 0; n < 4; ++n) {
            int col = bn + wc * 64 + n * 16 + lk;
            #pragma unroll
            for (int r = 0; r < 4; ++r) {
                float v = acc[m][n][r];
                if (EPI >= 1) v += bias[col];
                if (EPI == 2) {
                    // gelu tanh-approx: v * sigmoid(2u), overflow-safe
                    float u = v * 0.7978845608f * (1.0f + 0.044715f * v * v);
                    v = v / (1.0f + __expf(-2.0f * u));
                }
                if (OUT_BF)
                    ((unsigned short*)Cout)[(size_t)(row + r) * ldc + col] = f2bf(v);
                else
                    ((float*)Cout)[(size_t)(row + r) * ldc + col] = v;
            }
        }
    }
}

// ---------------------------------------------------------------------------
// fp32 -> bf16 flat convert, 4 elems/thread
// ---------------------------------------------------------------------------
__global__ __launch_bounds__(256) void cvt_bf16(
    const float* __restrict__ src, unsigned short* __restrict__ dst, int n)
{
    int i = (blockIdx.x * 256 + threadIdx.x) * 4;
    if (i < n) {
        float4 v = *(const float4*)(src + i);
        u16x4 o = { f2bf(v.x), f2bf(v.y), f2bf(v.z), f2bf(v.w) };
        *(u16x4*)(dst + i) = o;
    }
}

// ---------------------------------------------------------------------------
// transpose + convert: src [R][Cc] f32 -> dst [Cc][R] bf16 (for B^T weights)
// ---------------------------------------------------------------------------
__global__ __launch_bounds__(256) void transpose_cvt(
    const float* __restrict__ src, unsigned short* __restrict__ dst, int R, int Cc)
{
    __shared__ float t[32][33];
    const int bc = blockIdx.x * 32, br = blockIdx.y * 32;
    const int tx = threadIdx.x & 31, ty = threadIdx.x >> 5;
    #pragma unroll
    for (int i = 0; i < 4; ++i)
        t[ty + i * 8][tx] = src[(size_t)(br + ty + i * 8) * Cc + bc + tx];
    __syncthreads();
    #pragma unroll
    for (int i = 0; i < 4; ++i)
        dst[(size_t)(bc + ty + i * 8) * R + br + tx] = f2bf(t[tx][ty + i * 8]);
}

// ---------------------------------------------------------------------------
// drofe on bf16 QK [M][2048] -> rotated bf16 Q [M][1024] (scale folded), K.
// ---------------------------------------------------------------------------
__global__ __launch_bounds__(256) void drofe_bf(
    const unsigned short* __restrict__ QK, unsigned short* __restrict__ Qo,
    unsigned short* __restrict__ Ko,
    const float* __restrict__ freqband, const float* __restrict__ demo, int N)
{
    const float PI_F = 3.14159265358979323846f;
    int idx = blockIdx.x * 256 + threadIdx.x;
    int col2 = idx & 511;
    int row  = idx >> 9;
    int n = row & (N - 1), b = row >> 10;
    int i  = col2 & 31;
    int ii = (i < 16) ? i : i - 16;
    float fb = (i < 16) ? freqband[n * 2 + 0] : freqband[n * 2 + 1];
    float freq = (1.0f + (float)ii * (4.0f / 15.0f)) * PI_F;
    float ang = fb * freq;
    float cv = cosf(ang), sv = sinf(ang);
    float ca = cv * demo[b * 2 + 0];
    float sg = sv * demo[b * 2 + 1];
    const unsigned* qk = (const unsigned*)(QK + (size_t)row * 2048);
    unsigned qu = qk[col2], ku = qk[512 + col2];
    float qe = bf2f((unsigned short)qu), qo_ = bf2f((unsigned short)(qu >> 16));
    float ke = bf2f((unsigned short)ku), ko_ = bf2f((unsigned short)(ku >> 16));
    const float s8 = 0.125f;
    unsigned qres = (unsigned)f2bf((qe * ca - qo_ * sg) * s8)
                  | ((unsigned)f2bf((qo_ * ca + qe * sg) * s8) << 16);
    unsigned kres = (unsigned)f2bf(ke * ca - ko_ * sg)
                  | ((unsigned)f2bf(ko_ * ca + ke * sg) << 16);
    ((unsigned*)Qo)[(size_t)row * 512 + col2] = qres;
    ((unsigned*)Ko)[(size_t)row * 512 + col2] = kres;
}

// ---------------------------------------------------------------------------
// Flash attention, bf16 in/out, MFMA 16x16x32, fp32 accum. (round-4 verified)
// ---------------------------------------------------------------------------
__global__ __launch_bounds__(256) void attn_mfma(
    const unsigned short* __restrict__ Q, const unsigned short* __restrict__ K,
    const unsigned short* __restrict__ V, unsigned short* __restrict__ O,
    int B, int H, int N)
{
    __shared__ unsigned short Ks[64 * 64];
    __shared__ unsigned short Vt[64 * 72];
    __shared__ unsigned short Ps[4][16 * 72];

    const int bi = blockIdx.x;
    const int bh = (bi & 7) + 8 * ((bi >> 3) & 15);
    const int q0 = (bi >> 7) * 64;
    const int b = bh >> 4, h = bh & 15;
    const int tid = threadIdx.x;
    const int w = tid >> 6, lane = tid & 63;
    const int lg = lane >> 4, lk = lane & 15;

    bf16x8 qf[2];
    {
        const unsigned short* qrow = Q + (size_t)(b * N + q0 + w * 16 + lk) * 1024 + h * 64;
        qf[0] = *(const bf16x8*)(qrow + lg * 8);
        qf[1] = *(const bf16x8*)(qrow + 32 + lg * 8);
    }

    f32x4 o[4] = {};
    float mrow[4], lrow[4];
    #pragma unroll
    for (int r = 0; r < 4; ++r) { mrow[r] = -INFINITY; lrow[r] = 0.f; }

    for (int t0 = 0; t0 < N; t0 += 64) {
        const size_t kvbase = (size_t)(b * N + t0) * 1024 + h * 64;
        #pragma unroll
        for (int it = 0; it < 2; ++it) {
            int s = it * 256 + tid;
            int row = s >> 3, cb = (s & 7) << 4;
            int dby = cb ^ ((row & 7) << 4);
            GLL16(K + kvbase + (size_t)row * 1024 + (dby >> 1), &Ks[s * 8]);
        }
        {
            int c = tid >> 5, k0 = (tid & 31) * 2;
            const unsigned short* vp = V + kvbase + (size_t)k0 * 1024 + c * 8;
            u16x8 va = *(const u16x8*)vp;
            u16x8 vb = *(const u16x8*)(vp + 1024);
            #pragma unroll
            for (int j = 0; j < 8; ++j) {
                unsigned val = (unsigned)va[j] | ((unsigned)vb[j] << 16);
                *(unsigned*)&Vt[(c * 8 + j) * 72 + k0] = val;
            }
        }
        __syncthreads();

        f32x4 s4[4];
        #pragma unroll
        for (int sub = 0; sub < 4; ++sub) {
            f32x4 acc = {0.f, 0.f, 0.f, 0.f};
            #pragma unroll
            for (int kh = 0; kh < 2; ++kh) {
                int cc = (kh * 64 + lg * 16) ^ ((lk & 7) << 4);
                bf16x8 kf = *(const bf16x8*)&Ks[(sub * 16 + lk) * 64 + (cc >> 1)];
                acc = __builtin_amdgcn_mfma_f32_16x16x32_bf16(qf[kh], kf, acc, 0, 0, 0);
            }
            s4[sub] = acc;
        }

        #pragma unroll
        for (int r = 0; r < 4; ++r) {
            float tm = fmaxf(fmaxf(s4[0][r], s4[1][r]), fmaxf(s4[2][r], s4[3][r]));
            #pragma unroll
            for (int msk = 1; msk < 16; msk <<= 1) tm = fmaxf(tm, __shfl_xor(tm, msk));
            float mn = fmaxf(mrow[r], tm);
            float corr = __expf(mrow[r] - mn);
            mrow[r] = mn;
            float psum = 0.f;
            unsigned short pb[4];
            #pragma unroll
            for (int sub = 0; sub < 4; ++sub) {
                float p = __expf(s4[sub][r] - mn);
                psum += p;
                pb[sub] = f2bf(p);
            }
            #pragma unroll
            for (int msk = 1; msk < 16; msk <<= 1) psum += __shfl_xor(psum, msk);
            lrow[r] = lrow[r] * corr + psum;
            #pragma unroll
            for (int ds = 0; ds < 4; ++ds) o[ds][r] *= corr;
            int q = lg * 4 + r;
            #pragma unroll
            for (int sub = 0; sub < 4; ++sub)
                Ps[w][q * 72 + sub * 16 + lk] = pb[sub];
        }
        asm volatile("s_waitcnt lgkmcnt(0)" ::: "memory");

        #pragma unroll
        for (int kh = 0; kh < 2; ++kh) {
            bf16x8 pf = *(const bf16x8*)&Ps[w][lk * 72 + kh * 32 + lg * 8];
            #pragma unroll
            for (int ds = 0; ds < 4; ++ds) {
                bf16x8 vf = *(const bf16x8*)&Vt[(ds * 16 + lk) * 72 + kh * 32 + lg * 8];
                o[ds] = __builtin_amdgcn_mfma_f32_16x16x32_bf16(pf, vf, o[ds], 0, 0, 0);
            }
        }
        __syncthreads();
    }

    #pragma unroll
    for (int ds = 0; ds < 4; ++ds)
        #pragma unroll
        for (int r = 0; r < 4; ++r) {
            int q = lg * 4 + r;
            O[(size_t)(b * N + q0 + w * 16 + q) * 1024 + h * 64 + ds * 16 + lk] =
                f2bf(o[ds][r] / lrow[r]);
        }
}

// ---------------------------------------------------------------------------
// Fused residual + LayerNorm: out = LN(x + gamma*y) * w + b  (+ optional bf16)
// ---------------------------------------------------------------------------
__global__ __launch_bounds__(256) void ln_res_kernel(
    const float* __restrict__ x, const float* __restrict__ y,
    const float* __restrict__ gamma, const float* __restrict__ w,
    const float* __restrict__ bia, float* __restrict__ out,
    unsigned short* __restrict__ out_bf, int C)
{
    const int row = blockIdx.x;
    __shared__ float buf[1024];
    __shared__ float red[8];
    const size_t base = (size_t)row * C;
    float s = 0.f, ss = 0.f;
    for (int c = threadIdx.x; c < C; c += 256) {
        float v = x[base + c] + gamma[c] * y[base + c];
        buf[c] = v; s += v; ss += v * v;
    }
    #pragma unroll
    for (int msk = 1; msk < 64; msk <<= 1) { s += __shfl_xor(s, msk); ss += __shfl_xor(ss, msk); }
    int wv = threadIdx.x >> 6, lane = threadIdx.x & 63;
    if (lane == 0) { red[wv * 2] = s; red[wv * 2 + 1] = ss; }
    __syncthreads();
    if (threadIdx.x == 0) {
        float S = 0.f, SS = 0.f;
        #pragma unroll
        for (int i = 0; i < 4; ++i) { S += red[2 * i]; SS += red[2 * i + 1]; }
        red[0] = S; red[1] = SS;
    }
    __syncthreads();
    float mu = red[0] / C;
    float var = red[1] / C - mu * mu;
    float rstd = rsqrtf(var + 1e-5f);
    for (int c = threadIdx.x; c < C; c += 256) {
        float v = (buf[c] - mu) * rstd * w[c] + bia[c];
        out[base + c] = v;
        if (out_bf) out_bf[base + c] = f2bf(v);
    }
}

// ---------------------------------------------------------------------------
extern "C" void kernel_launch(void* const* d_in, const int* in_sizes, int n_in,
                              void* d_out, int out_size, void* d_ws, size_t ws_size,
                              hipStream_t stream)
{
    const float* x      = (const float*)d_in[0];
    const float* demo   = (const float*)d_in[1];
    const float* expl   = (const float*)d_in[2];
    const float* fb     = (const float*)d_in[3];
    const float* w_qkv  = (const float*)d_in[4];
    const float* w_proj = (const float*)d_in[5];
    const float* b_proj = (const float*)d_in[6];
    const float* gamma1 = (const float*)d_in[7];
    const float* gamma2 = (const float*)d_in[8];
    const float* ln1_w  = (const float*)d_in[9];
    const float* ln1_b  = (const float*)d_in[10];
    const float* ln2_w  = (const float*)d_in[11];
    const float* ln2_b  = (const float*)d_in[12];
    const float* w1     = (const float*)d_in[13];
    const float* b1     = (const float*)d_in[14];
    const float* w2     = (const float*)d_in[15];
    const float* b2     = (const float*)d_in[16];
    float* out = (float*)d_out;

    const int B = 8, N = 1024, C = 1024, F = 4096, H = 16;
    const int M = B * N;                        // 8192
    const size_t Mi = 1048576;

    float* ws = (float*)d_ws;
    unsigned short* QKbf = (unsigned short*)ws;              // M x 2048 bf16
    unsigned short* Obf  = (unsigned short*)ws;              // M x 1024 bf16
    float*          H2   = ws;                               // M x 1024 f32
    unsigned short* Qbf  = (unsigned short*)(ws + 8 * Mi);   // M x 1024 bf16
    unsigned short* Kbf  = (unsigned short*)(ws + 12 * Mi);
    unsigned short* Vbf  = (unsigned short*)(ws + 16 * Mi);
    unsigned short* Hid  = (unsigned short*)(ws + 8 * Mi);   // M x 4096 bf16
    unsigned short* Ebf  = (unsigned short*)(ws + 24 * Mi);
    unsigned short* Xbf  = (unsigned short*)(ws + 28 * Mi);
    float*          Pb   = ws + 24 * Mi;                     // M x 1024 f32
    float*          X1   = ws + 32 * Mi;                     // M x 1024 f32
    unsigned short* X1bf = (unsigned short*)(ws + 40 * Mi);
    unsigned short* Wt   = (unsigned short*)(ws + 44 * Mi);
    unsigned short* wqkvT  = Wt;                             // [3072][1024]
    unsigned short* wprojT = Wt + (size_t)3145728;           // [1024][1024]
    unsigned short* w1T    = wprojT + (size_t)1048576;       // [4096][1024]
    unsigned short* w2T    = w1T + (size_t)4194304;          // [1024][4096]

    dim3 blk(256);
    const int MC = M * C;

    hipLaunchKernelGGL(cvt_bf16, dim3(MC / 1024), blk, 0, stream, expl, Ebf, MC);
    hipLaunchKernelGGL(cvt_bf16, dim3(MC / 1024), blk, 0, stream, x, Xbf, MC);
    hipLaunchKernelGGL(transpose_cvt, dim3(96, 32), blk, 0, stream, w_qkv, wqkvT, C, 3 * C);
    hipLaunchKernelGGL(transpose_cvt, dim3(32, 32), blk, 0, stream, w_proj, wprojT, C, C);
    hipLaunchKernelGGL(transpose_cvt, dim3(128, 32), blk, 0, stream, w1, w1T, C, F);
    hipLaunchKernelGGL(transpose_cvt, dim3(32, 128), blk, 0, stream, w2, w2T, F, C);

    // QK projection (explanation) -> bf16; V projection (x) -> bf16  [BK=32]
    hipLaunchKernelGGL((gemm97<0,1,32>), dim3(64 * 16), blk, 0, stream, Ebf, wqkvT, (const float*)nullptr, (void*)QKbf, M, 2048, C, 2048);
    hipLaunchKernelGGL((gemm97<0,1,32>), dim3(64 * 8), blk, 0, stream, Xbf, wqkvT + (size_t)2048 * 1024, (const float*)nullptr, (void*)Vbf, M, 1024, C, 1024);

    // drofe: bf16 QK -> rotated bf16 Q (scaled), K
    hipLaunchKernelGGL(drofe_bf, dim3(M * 512 / 256), blk, 0, stream, QKbf, Qbf, Kbf, fb, demo, N);

    // attention -> bf16 O
    hipLaunchKernelGGL(attn_mfma, dim3(B * H * (N / 64)), blk, 0, stream, Qbf, Kbf, Vbf, Obf, B, H, N);

    // output projection [BK=32]
    hipLaunchKernelGGL((gemm97<1,0,32>), dim3(64 * 8), blk, 0, stream, Obf, wprojT, b_proj, (void*)Pb, M, 1024, C, 1024);

    // residual + LN1 (f32 + bf16)
    hipLaunchKernelGGL(ln_res_kernel, dim3(M), blk, 0, stream, x, Pb, gamma1, ln1_w, ln1_b, X1, X1bf, C);

    // MLP: MLP1 [BK=32, fast gelu], MLP2 [BK=64, K=4096]
    hipLaunchKernelGGL((gemm97<2,1,32>), dim3(64 * 32), blk, 0, stream, X1bf, w1T, b1, (void*)Hid, M, F, C, F);
    hipLaunchKernelGGL((gemm97<1,0,64>), dim3(64 * 8), blk, 0, stream, Hid, w2T, b2, (void*)H2, M, 1024, F, 1024);

    // residual + LN2 -> out
    hipLaunchKernelGGL(ln_res_kernel, dim3(M), blk, 0, stream, X1, H2, gamma2, ln2_w, ln2_b, out, (unsigned short*)nullptr, C);
}

// Round 10
// 504.088 us; speedup vs baseline: 1.1171x; 1.0091x over previous
//
#include <hip/hip_runtime.h>
#include <hip/hip_bf16.h>
#include <math.h>

typedef __attribute__((ext_vector_type(8))) short bf16x8;
typedef __attribute__((ext_vector_type(8))) unsigned short u16x8;
typedef __attribute__((ext_vector_type(4))) float f32x4;
typedef __attribute__((ext_vector_type(4))) unsigned short u16x4;

__device__ inline unsigned short f2bf(float f) {
    union { float f; unsigned u; } v; v.f = f;
    unsigned r = (v.u + 0x7fff + ((v.u >> 16) & 1)) >> 16;   // RNE
    return (unsigned short)r;
}
__device__ inline float bf2f(unsigned short u) {
    union { unsigned u; float f; } v; v.u = ((unsigned)u) << 16; return v.f;
}

#define GLL16(gp, lp) __builtin_amdgcn_global_load_lds(                      \
    (const __attribute__((address_space(1))) void*)(gp),                     \
    (__attribute__((address_space(3))) void*)(lp), 16, 0, 0)

// ---------------------------------------------------------------------------
// bf16 MFMA GEMM, m97 structure, templated BK:
// 128x128 tile, 4 waves (2x2), per-wave 64x64 = 4x4 frags of 16x16x32.
// Single-buffered LDS: BK=32 -> 16KB, BK=64 -> 32KB. Barrier drain covered by
// resident-block overlap (m114; measured r5/r6/r8: pipelining that cuts
// blocks/CU loses).
// Swizzle (rule-21 involution, stage source + read slot):
//   BK=64 (128B rows): f(r) = r&7            -> 2-way max (r7: 0 conflicts)
//   BK=32 (64B rows):  f(r) = (r^(r>>2))&3   -> 2-way max (fixes r9's 4-way:
//     64B rows alternate only 2 bank-phases, so slot must mix bit r>>2)
// EPI: 0=none 1=+bias 2=+bias+gelu(tanh-approx, sigmoid form).
// ---------------------------------------------------------------------------
template<int EPI, int OUT_BF, int BK>
__global__ __launch_bounds__(256) void gemm97(
    const unsigned short* __restrict__ A,
    const unsigned short* __restrict__ Bt,
    const float* __restrict__ bias,
    void* __restrict__ Cout,
    int M, int Nn, int K, int ldc)
{
    constexpr int SPR = BK / 8;                 // 16B slots per row (4 or 8)
    constexpr int RB  = BK * 2;                 // row bytes
    __shared__ unsigned char lds[256 * BK * 2]; // A 128 rows ++ B 128 rows
    const int tid = threadIdx.x;
    const int w = tid >> 6, lane = tid & 63;
    const int lk = lane & 15, lg = lane >> 4;
    const int wr = w >> 1, wc = w & 1;
    const int nbn = Nn >> 7;
    const int nb = gridDim.x;
    int bid = blockIdx.x;
    int swz = (nb & 7) ? bid : (bid & 7) * (nb >> 3) + (bid >> 3);  // XCD swizzle
    const int bm = (swz / nbn) << 7, bn = (swz % nbn) << 7;

    f32x4 acc[4][4] = {};

    for (int k0 = 0; k0 < K; k0 += BK) {
        #pragma unroll
        for (int i = 0; i < SPR; ++i) {         // 256*SPR slots of 16B
            int s = tid + i * 256;
            int r = s / SPR, c = s % SPR;
            int cs;
            if constexpr (SPR == 4) cs = (c ^ r ^ (r >> 2)) & 3;
            else                    cs = c ^ (r & 7);
            const unsigned short* gp = (r < 128)
                ? A  + (size_t)(bm + r) * K + k0 + cs * 8
                : Bt + (size_t)(bn + (r - 128)) * K + k0 + cs * 8;
            GLL16(gp, &lds[s * 16]);
        }
        __syncthreads();                        // compiler drains vmcnt

        #pragma unroll
        for (int kk = 0; kk < BK / 32; ++kk) {
            bf16x8 af[4], bfr[4];
            #pragma unroll
            for (int m = 0; m < 4; ++m) {
                int row = wr * 64 + m * 16 + lk;
                int sl;
                if constexpr (SPR == 4) sl = ((kk * 4 + lg) ^ row ^ (row >> 2)) & 3;
                else                    sl = (kk * 4 + lg) ^ (row & 7);
                af[m] = *(const bf16x8*)&lds[row * RB + sl * 16];
            }
            #pragma unroll
            for (int n = 0; n < 4; ++n) {
                int row = wc * 64 + n * 16 + lk;
                int sl;
                if constexpr (SPR == 4) sl = ((kk * 4 + lg) ^ row ^ (row >> 2)) & 3;
                else                    sl = (kk * 4 + lg) ^ (row & 7);
                bfr[n] = *(const bf16x8*)&lds[128 * RB + row * RB + sl * 16];
            }
            #pragma unroll
            for (int m = 0; m < 4; ++m)
                #pragma unroll
                for (int n = 0; n < 4; ++n)
                    acc[m][n] = __builtin_amdgcn_mfma_f32_16x16x32_bf16(af[m], bfr[n], acc[m][n], 0, 0, 0);
        }
        __syncthreads();
    }

    #pragma unroll
    for (int m = 0; m < 4; ++m) {
        int row = bm + wr * 64 + m * 16 + lg * 4;
        #pragma unroll
        for (int n = 0; n < 4; ++n) {
            int col = bn + wc * 64 + n * 16 + lk;
            #pragma unroll
            for (int r = 0; r < 4; ++r) {
                float v = acc[m][n][r];
                if (EPI >= 1) v += bias[col];
                if (EPI == 2) {
                    // gelu tanh-approx: v * sigmoid(2u), overflow-safe
                    float u = v * 0.7978845608f * (1.0f + 0.044715f * v * v);
                    v = v / (1.0f + __expf(-2.0f * u));
                }
                if (OUT_BF)
                    ((unsigned short*)Cout)[(size_t)(row + r) * ldc + col] = f2bf(v);
                else
                    ((float*)Cout)[(size_t)(row + r) * ldc + col] = v;
            }
        }
    }
}

// ---------------------------------------------------------------------------
// fp32 -> bf16 flat convert, 4 elems/thread
// ---------------------------------------------------------------------------
__global__ __launch_bounds__(256) void cvt_bf16(
    const float* __restrict__ src, unsigned short* __restrict__ dst, int n)
{
    int i = (blockIdx.x * 256 + threadIdx.x) * 4;
    if (i < n) {
        float4 v = *(const float4*)(src + i);
        u16x4 o = { f2bf(v.x), f2bf(v.y), f2bf(v.z), f2bf(v.w) };
        *(u16x4*)(dst + i) = o;
    }
}

// ---------------------------------------------------------------------------
// transpose + convert: src [R][Cc] f32 -> dst [Cc][R] bf16 (for B^T weights)
// ---------------------------------------------------------------------------
__global__ __launch_bounds__(256) void transpose_cvt(
    const float* __restrict__ src, unsigned short* __restrict__ dst, int R, int Cc)
{
    __shared__ float t[32][33];
    const int bc = blockIdx.x * 32, br = blockIdx.y * 32;
    const int tx = threadIdx.x & 31, ty = threadIdx.x >> 5;
    #pragma unroll
    for (int i = 0; i < 4; ++i)
        t[ty + i * 8][tx] = src[(size_t)(br + ty + i * 8) * Cc + bc + tx];
    __syncthreads();
    #pragma unroll
    for (int i = 0; i < 4; ++i)
        dst[(size_t)(bc + ty + i * 8) * R + br + tx] = f2bf(t[tx][ty + i * 8]);
}

// ---------------------------------------------------------------------------
// drofe on bf16 QK [M][2048] -> rotated bf16 Q [M][1024] (scale folded), K.
// ---------------------------------------------------------------------------
__global__ __launch_bounds__(256) void drofe_bf(
    const unsigned short* __restrict__ QK, unsigned short* __restrict__ Qo,
    unsigned short* __restrict__ Ko,
    const float* __restrict__ freqband, const float* __restrict__ demo, int N)
{
    const float PI_F = 3.14159265358979323846f;
    int idx = blockIdx.x * 256 + threadIdx.x;
    int col2 = idx & 511;
    int row  = idx >> 9;
    int n = row & (N - 1), b = row >> 10;
    int i  = col2 & 31;
    int ii = (i < 16) ? i : i - 16;
    float fb = (i < 16) ? freqband[n * 2 + 0] : freqband[n * 2 + 1];
    float freq = (1.0f + (float)ii * (4.0f / 15.0f)) * PI_F;
    float ang = fb * freq;
    float cv = cosf(ang), sv = sinf(ang);
    float ca = cv * demo[b * 2 + 0];
    float sg = sv * demo[b * 2 + 1];
    const unsigned* qk = (const unsigned*)(QK + (size_t)row * 2048);
    unsigned qu = qk[col2], ku = qk[512 + col2];
    float qe = bf2f((unsigned short)qu), qo_ = bf2f((unsigned short)(qu >> 16));
    float ke = bf2f((unsigned short)ku), ko_ = bf2f((unsigned short)(ku >> 16));
    const float s8 = 0.125f;
    unsigned qres = (unsigned)f2bf((qe * ca - qo_ * sg) * s8)
                  | ((unsigned)f2bf((qo_ * ca + qe * sg) * s8) << 16);
    unsigned kres = (unsigned)f2bf(ke * ca - ko_ * sg)
                  | ((unsigned)f2bf(ko_ * ca + ke * sg) << 16);
    ((unsigned*)Qo)[(size_t)row * 512 + col2] = qres;
    ((unsigned*)Ko)[(size_t)row * 512 + col2] = kres;
}

// ---------------------------------------------------------------------------
// Flash attention, bf16 in/out, MFMA 16x16x32, fp32 accum.
// r10: Ps slot-XOR swizzle keyed on (q>>2) — kills the 4-way ds_write_u16
// conflict (rows q,q+8 are 0 mod 32 banks apart at 144B stride); P cast by
// truncation (P in [0,1], bias 2^-8 << threshold) cuts ~48 VALU/tile-wave.
// ---------------------------------------------------------------------------
__global__ __launch_bounds__(256) void attn_mfma(
    const unsigned short* __restrict__ Q, const unsigned short* __restrict__ K,
    const unsigned short* __restrict__ V, unsigned short* __restrict__ O,
    int B, int H, int N)
{
    __shared__ unsigned short Ks[64 * 64];
    __shared__ unsigned short Vt[64 * 72];
    __shared__ unsigned short Ps[4][16 * 72];

    const int bi = blockIdx.x;
    const int bh = (bi & 7) + 8 * ((bi >> 3) & 15);
    const int q0 = (bi >> 7) * 64;
    const int b = bh >> 4, h = bh & 15;
    const int tid = threadIdx.x;
    const int w = tid >> 6, lane = tid & 63;
    const int lg = lane >> 4, lk = lane & 15;

    bf16x8 qf[2];
    {
        const unsigned short* qrow = Q + (size_t)(b * N + q0 + w * 16 + lk) * 1024 + h * 64;
        qf[0] = *(const bf16x8*)(qrow + lg * 8);
        qf[1] = *(const bf16x8*)(qrow + 32 + lg * 8);
    }

    f32x4 o[4] = {};
    float mrow[4], lrow[4];
    #pragma unroll
    for (int r = 0; r < 4; ++r) { mrow[r] = -INFINITY; lrow[r] = 0.f; }

    for (int t0 = 0; t0 < N; t0 += 64) {
        const size_t kvbase = (size_t)(b * N + t0) * 1024 + h * 64;
        #pragma unroll
        for (int it = 0; it < 2; ++it) {
            int s = it * 256 + tid;
            int row = s >> 3, cb = (s & 7) << 4;
            int dby = cb ^ ((row & 7) << 4);
            GLL16(K + kvbase + (size_t)row * 1024 + (dby >> 1), &Ks[s * 8]);
        }
        {
            int c = tid >> 5, k0 = (tid & 31) * 2;
            const unsigned short* vp = V + kvbase + (size_t)k0 * 1024 + c * 8;
            u16x8 va = *(const u16x8*)vp;
            u16x8 vb = *(const u16x8*)(vp + 1024);
            #pragma unroll
            for (int j = 0; j < 8; ++j) {
                unsigned val = (unsigned)va[j] | ((unsigned)vb[j] << 16);
                *(unsigned*)&Vt[(c * 8 + j) * 72 + k0] = val;
            }
        }
        __syncthreads();

        f32x4 s4[4];
        #pragma unroll
        for (int sub = 0; sub < 4; ++sub) {
            f32x4 acc = {0.f, 0.f, 0.f, 0.f};
            #pragma unroll
            for (int kh = 0; kh < 2; ++kh) {
                int cc = (kh * 64 + lg * 16) ^ ((lk & 7) << 4);
                bf16x8 kf = *(const bf16x8*)&Ks[(sub * 16 + lk) * 64 + (cc >> 1)];
                acc = __builtin_amdgcn_mfma_f32_16x16x32_bf16(qf[kh], kf, acc, 0, 0, 0);
            }
            s4[sub] = acc;
        }

        #pragma unroll
        for (int r = 0; r < 4; ++r) {
            float tm = fmaxf(fmaxf(s4[0][r], s4[1][r]), fmaxf(s4[2][r], s4[3][r]));
            #pragma unroll
            for (int msk = 1; msk < 16; msk <<= 1) tm = fmaxf(tm, __shfl_xor(tm, msk));
            float mn = fmaxf(mrow[r], tm);
            float corr = __expf(mrow[r] - mn);
            mrow[r] = mn;
            float psum = 0.f;
            unsigned short pb[4];
            #pragma unroll
            for (int sub = 0; sub < 4; ++sub) {
                float p = __expf(s4[sub][r] - mn);
                psum += p;
                pb[sub] = (unsigned short)(__float_as_uint(p) >> 16);  // trunc
            }
            #pragma unroll
            for (int msk = 1; msk < 16; msk <<= 1) psum += __shfl_xor(psum, msk);
            lrow[r] = lrow[r] * corr + psum;
            #pragma unroll
            for (int ds = 0; ds < 4; ++ds) o[ds][r] *= corr;
            int q = lg * 4 + r;
            #pragma unroll
            for (int sub = 0; sub < 4; ++sub)
                Ps[w][q * 72 + (((sub * 16 + lk) ^ ((q >> 2) << 3)))] = pb[sub];
        }
        asm volatile("s_waitcnt lgkmcnt(0)" ::: "memory");

        #pragma unroll
        for (int kh = 0; kh < 2; ++kh) {
            bf16x8 pf = *(const bf16x8*)&Ps[w][lk * 72 + ((kh * 32 + lg * 8) ^ ((lk >> 2) << 3))];
            #pragma unroll
            for (int ds = 0; ds < 4; ++ds) {
                bf16x8 vf = *(const bf16x8*)&Vt[(ds * 16 + lk) * 72 + kh * 32 + lg * 8];
                o[ds] = __builtin_amdgcn_mfma_f32_16x16x32_bf16(pf, vf, o[ds], 0, 0, 0);
            }
        }
        __syncthreads();
    }

    #pragma unroll
    for (int ds = 0; ds < 4; ++ds)
        #pragma unroll
        for (int r = 0; r < 4; ++r) {
            int q = lg * 4 + r;
            O[(size_t)(b * N + q0 + w * 16 + q) * 1024 + h * 64 + ds * 16 + lk] =
                f2bf(o[ds][r] / lrow[r]);
        }
}

// ---------------------------------------------------------------------------
// Fused residual + LayerNorm: out = LN(x + gamma*y) * w + b  (+ optional bf16)
// ---------------------------------------------------------------------------
__global__ __launch_bounds__(256) void ln_res_kernel(
    const float* __restrict__ x, const float* __restrict__ y,
    const float* __restrict__ gamma, const float* __restrict__ w,
    const float* __restrict__ bia, float* __restrict__ out,
    unsigned short* __restrict__ out_bf, int C)
{
    const int row = blockIdx.x;
    __shared__ float buf[1024];
    __shared__ float red[8];
    const size_t base = (size_t)row * C;
    float s = 0.f, ss = 0.f;
    for (int c = threadIdx.x; c < C; c += 256) {
        float v = x[base + c] + gamma[c] * y[base + c];
        buf[c] = v; s += v; ss += v * v;
    }
    #pragma unroll
    for (int msk = 1; msk < 64; msk <<= 1) { s += __shfl_xor(s, msk); ss += __shfl_xor(ss, msk); }
    int wv = threadIdx.x >> 6, lane = threadIdx.x & 63;
    if (lane == 0) { red[wv * 2] = s; red[wv * 2 + 1] = ss; }
    __syncthreads();
    if (threadIdx.x == 0) {
        float S = 0.f, SS = 0.f;
        #pragma unroll
        for (int i = 0; i < 4; ++i) { S += red[2 * i]; SS += red[2 * i + 1]; }
        red[0] = S; red[1] = SS;
    }
    __syncthreads();
    float mu = red[0] / C;
    float var = red[1] / C - mu * mu;
    float rstd = rsqrtf(var + 1e-5f);
    for (int c = threadIdx.x; c < C; c += 256) {
        float v = (buf[c] - mu) * rstd * w[c] + bia[c];
        out[base + c] = v;
        if (out_bf) out_bf[base + c] = f2bf(v);
    }
}

// ---------------------------------------------------------------------------
extern "C" void kernel_launch(void* const* d_in, const int* in_sizes, int n_in,
                              void* d_out, int out_size, void* d_ws, size_t ws_size,
                              hipStream_t stream)
{
    const float* x      = (const float*)d_in[0];
    const float* demo   = (const float*)d_in[1];
    const float* expl   = (const float*)d_in[2];
    const float* fb     = (const float*)d_in[3];
    const float* w_qkv  = (const float*)d_in[4];
    const float* w_proj = (const float*)d_in[5];
    const float* b_proj = (const float*)d_in[6];
    const float* gamma1 = (const float*)d_in[7];
    const float* gamma2 = (const float*)d_in[8];
    const float* ln1_w  = (const float*)d_in[9];
    const float* ln1_b  = (const float*)d_in[10];
    const float* ln2_w  = (const float*)d_in[11];
    const float* ln2_b  = (const float*)d_in[12];
    const float* w1     = (const float*)d_in[13];
    const float* b1     = (const float*)d_in[14];
    const float* w2     = (const float*)d_in[15];
    const float* b2     = (const float*)d_in[16];
    float* out = (float*)d_out;

    const int B = 8, N = 1024, C = 1024, F = 4096, H = 16;
    const int M = B * N;                        // 8192
    const size_t Mi = 1048576;

    float* ws = (float*)d_ws;
    unsigned short* QKbf = (unsigned short*)ws;              // M x 2048 bf16
    unsigned short* Obf  = (unsigned short*)ws;              // M x 1024 bf16
    float*          H2   = ws;                               // M x 1024 f32
    unsigned short* Qbf  = (unsigned short*)(ws + 8 * Mi);   // M x 1024 bf16
    unsigned short* Kbf  = (unsigned short*)(ws + 12 * Mi);
    unsigned short* Vbf  = (unsigned short*)(ws + 16 * Mi);
    unsigned short* Hid  = (unsigned short*)(ws + 8 * Mi);   // M x 4096 bf16
    unsigned short* Ebf  = (unsigned short*)(ws + 24 * Mi);
    unsigned short* Xbf  = (unsigned short*)(ws + 28 * Mi);
    float*          Pb   = ws + 24 * Mi;                     // M x 1024 f32
    float*          X1   = ws + 32 * Mi;                     // M x 1024 f32
    unsigned short* X1bf = (unsigned short*)(ws + 40 * Mi);
    unsigned short* Wt   = (unsigned short*)(ws + 44 * Mi);
    unsigned short* wqkvT  = Wt;                             // [3072][1024]
    unsigned short* wprojT = Wt + (size_t)3145728;           // [1024][1024]
    unsigned short* w1T    = wprojT + (size_t)1048576;       // [4096][1024]
    unsigned short* w2T    = w1T + (size_t)4194304;          // [1024][4096]

    dim3 blk(256);
    const int MC = M * C;

    hipLaunchKernelGGL(cvt_bf16, dim3(MC / 1024), blk, 0, stream, expl, Ebf, MC);
    hipLaunchKernelGGL(cvt_bf16, dim3(MC / 1024), blk, 0, stream, x, Xbf, MC);
    hipLaunchKernelGGL(transpose_cvt, dim3(96, 32), blk, 0, stream, w_qkv, wqkvT, C, 3 * C);
    hipLaunchKernelGGL(transpose_cvt, dim3(32, 32), blk, 0, stream, w_proj, wprojT, C, C);
    hipLaunchKernelGGL(transpose_cvt, dim3(128, 32), blk, 0, stream, w1, w1T, C, F);
    hipLaunchKernelGGL(transpose_cvt, dim3(32, 128), blk, 0, stream, w2, w2T, F, C);

    // QK projection (explanation) -> bf16; V projection (x) -> bf16  [BK=32]
    hipLaunchKernelGGL((gemm97<0,1,32>), dim3(64 * 16), blk, 0, stream, Ebf, wqkvT, (const float*)nullptr, (void*)QKbf, M, 2048, C, 2048);
    hipLaunchKernelGGL((gemm97<0,1,32>), dim3(64 * 8), blk, 0, stream, Xbf, wqkvT + (size_t)2048 * 1024, (const float*)nullptr, (void*)Vbf, M, 1024, C, 1024);

    // drofe: bf16 QK -> rotated bf16 Q (scaled), K
    hipLaunchKernelGGL(drofe_bf, dim3(M * 512 / 256), blk, 0, stream, QKbf, Qbf, Kbf, fb, demo, N);

    // attention -> bf16 O
    hipLaunchKernelGGL(attn_mfma, dim3(B * H * (N / 64)), blk, 0, stream, Qbf, Kbf, Vbf, Obf, B, H, N);

    // output projection [BK=32]
    hipLaunchKernelGGL((gemm97<1,0,32>), dim3(64 * 8), blk, 0, stream, Obf, wprojT, b_proj, (void*)Pb, M, 1024, C, 1024);

    // residual + LN1 (f32 + bf16)
    hipLaunchKernelGGL(ln_res_kernel, dim3(M), blk, 0, stream, x, Pb, gamma1, ln1_w, ln1_b, X1, X1bf, C);

    // MLP: MLP1 [BK=32, fast gelu], MLP2 [BK=64, K=4096]
    hipLaunchKernelGGL((gemm97<2,1,32>), dim3(64 * 32), blk, 0, stream, X1bf, w1T, b1, (void*)Hid, M, F, C, F);
    hipLaunchKernelGGL((gemm97<1,0,64>), dim3(64 * 8), blk, 0, stream, Hid, w2T, b2, (void*)H2, M, 1024, F, 1024);

    // residual + LN2 -> out
    hipLaunchKernelGGL(ln_res_kernel, dim3(M), blk, 0, stream, X1, H2, gamma2, ln2_w, ln2_b, out, (unsigned short*)nullptr, C);
}

// Round 11
// 464.910 us; speedup vs baseline: 1.2112x; 1.0843x over previous
//
#include <hip/hip_runtime.h>
#include <hip/hip_bf16.h>
#include <math.h>

typedef __attribute__((ext_vector_type(8))) short bf16x8;
typedef __attribute__((ext_vector_type(8))) unsigned short u16x8;
typedef __attribute__((ext_vector_type(4))) float f32x4;
typedef __attribute__((ext_vector_type(4))) unsigned short u16x4;

__device__ inline unsigned short f2bf(float f) {
    union { float f; unsigned u; } v; v.f = f;
    unsigned r = (v.u + 0x7fff + ((v.u >> 16) & 1)) >> 16;   // RNE
    return (unsigned short)r;
}
__device__ inline float bf2f(unsigned short u) {
    union { unsigned u; float f; } v; v.u = ((unsigned)u) << 16; return v.f;
}

#define GLL16(gp, lp) __builtin_amdgcn_global_load_lds(                      \
    (const __attribute__((address_space(1))) void*)(gp),                     \
    (__attribute__((address_space(3))) void*)(lp), 16, 0, 0)

// ---------------------------------------------------------------------------
// bf16 MFMA GEMM, 2-phase stage-early double-buffered (T3 minimum recipe,
// m248-verified 655-666 TF @256^2/K=1024): 256x256 tile, BK=32, 8 waves (2x4),
// per-wave 128x64 = 8x4 frags. Loop: STAGE(t+1 into buf^1) BEFORE ds_read+MFMA
// of buf — load latency hides under compute; ONE __syncthreads per tile
// (compiler emits the vmcnt/lgkm drain there). 64KB dbuf LDS.
// Swizzle: r10's involution (c^r^(r>>2))&3 on stage source + read slot;
// residual 2-way aliasing of 64B rows is free (m136; r10 A/B: no timing cost).
// Use only where grid >= 256 blocks (QK, MLP1).
// ---------------------------------------------------------------------------
template<int EPI, int OUT_BF>
__global__ __launch_bounds__(512) void gemm2ph(
    const unsigned short* __restrict__ A,
    const unsigned short* __restrict__ Bt,
    const float* __restrict__ bias,
    void* __restrict__ Cout,
    int M, int Nn, int K, int ldc)
{
    __shared__ unsigned char lds[2][32768];     // per buf: A 16KB ++ B 16KB
    const int tid = threadIdx.x;
    const int w = tid >> 6, lane = tid & 63;
    const int lk = lane & 15, lg = lane >> 4;
    const int wr = w >> 2, wc = w & 3;          // 2 x 4 wave grid
    const int nbn = Nn >> 8;
    const int nb = gridDim.x;
    int bid = blockIdx.x;
    int swz = (nb & 7) ? bid : (bid & 7) * (nb >> 3) + (bid >> 3);  // XCD swizzle
    const int bm = (swz / nbn) << 8, bn = (swz % nbn) << 8;

    f32x4 acc[8][4] = {};

    auto stage = [&](int buf, int k0) {
        #pragma unroll
        for (int i = 0; i < 4; ++i) {           // 2048 slots of 16B
            int s = tid + i * 512;
            int r = s >> 2, c = s & 3;
            int cs = (c ^ r ^ (r >> 2)) & 3;
            const unsigned short* gp = (r < 256)
                ? A  + (size_t)(bm + r) * K + k0 + cs * 8
                : Bt + (size_t)(bn + (r - 256)) * K + k0 + cs * 8;
            GLL16(gp, &lds[buf][s * 16]);
        }
    };

    const int NT = K >> 5;
    stage(0, 0);
    __syncthreads();                            // prologue drain
    int cur = 0;
    for (int t = 0; t < NT; ++t) {
        if (t + 1 < NT) stage(cur ^ 1, (t + 1) << 5);   // issue-early prefetch
        bf16x8 af[8], bfr[4];
        #pragma unroll
        for (int mi = 0; mi < 8; ++mi) {
            int row = wr * 128 + mi * 16 + lk;
            int sl = (lg ^ row ^ (row >> 2)) & 3;
            af[mi] = *(const bf16x8*)&lds[cur][row * 64 + sl * 16];
        }
        #pragma unroll
        for (int nj = 0; nj < 4; ++nj) {
            int row = wc * 64 + nj * 16 + lk;
            int sl = (lg ^ row ^ (row >> 2)) & 3;
            bfr[nj] = *(const bf16x8*)&lds[cur][16384 + row * 64 + sl * 16];
        }
        #pragma unroll
        for (int mi = 0; mi < 8; ++mi)
            #pragma unroll
            for (int nj = 0; nj < 4; ++nj)
                acc[mi][nj] = __builtin_amdgcn_mfma_f32_16x16x32_bf16(af[mi], bfr[nj], acc[mi][nj], 0, 0, 0);
        __syncthreads();                        // one barrier/tile: buf^1 ready, cur free
        cur ^= 1;
    }

    #pragma unroll
    for (int mi = 0; mi < 8; ++mi) {
        int row = bm + wr * 128 + mi * 16 + lg * 4;
        #pragma unroll
        for (int nj = 0; nj < 4; ++nj) {
            int col = bn + wc * 64 + nj * 16 + lk;
            #pragma unroll
            for (int r = 0; r < 4; ++r) {
                float v = acc[mi][nj][r];
                if (EPI >= 1) v += bias[col];
                if (EPI == 2) {
                    float u = v * 0.7978845608f * (1.0f + 0.044715f * v * v);
                    v = v / (1.0f + __expf(-2.0f * u));
                }
                if (OUT_BF)
                    ((unsigned short*)Cout)[(size_t)(row + r) * ldc + col] = f2bf(v);
                else
                    ((float*)Cout)[(size_t)(row + r) * ldc + col] = v;
            }
        }
    }
}

// ---------------------------------------------------------------------------
// bf16 MFMA GEMM, m97 structure, templated BK (r7/r10-verified).
// ---------------------------------------------------------------------------
template<int EPI, int OUT_BF, int BK>
__global__ __launch_bounds__(256) void gemm97(
    const unsigned short* __restrict__ A,
    const unsigned short* __restrict__ Bt,
    const float* __restrict__ bias,
    void* __restrict__ Cout,
    int M, int Nn, int K, int ldc)
{
    constexpr int SPR = BK / 8;
    constexpr int RB  = BK * 2;
    __shared__ unsigned char lds[256 * BK * 2];
    const int tid = threadIdx.x;
    const int w = tid >> 6, lane = tid & 63;
    const int lk = lane & 15, lg = lane >> 4;
    const int wr = w >> 1, wc = w & 1;
    const int nbn = Nn >> 7;
    const int nb = gridDim.x;
    int bid = blockIdx.x;
    int swz = (nb & 7) ? bid : (bid & 7) * (nb >> 3) + (bid >> 3);
    const int bm = (swz / nbn) << 7, bn = (swz % nbn) << 7;

    f32x4 acc[4][4] = {};

    for (int k0 = 0; k0 < K; k0 += BK) {
        #pragma unroll
        for (int i = 0; i < SPR; ++i) {
            int s = tid + i * 256;
            int r = s / SPR, c = s % SPR;
            int cs;
            if constexpr (SPR == 4) cs = (c ^ r ^ (r >> 2)) & 3;
            else                    cs = c ^ (r & 7);
            const unsigned short* gp = (r < 128)
                ? A  + (size_t)(bm + r) * K + k0 + cs * 8
                : Bt + (size_t)(bn + (r - 128)) * K + k0 + cs * 8;
            GLL16(gp, &lds[s * 16]);
        }
        __syncthreads();

        #pragma unroll
        for (int kk = 0; kk < BK / 32; ++kk) {
            bf16x8 af[4], bfr[4];
            #pragma unroll
            for (int m = 0; m < 4; ++m) {
                int row = wr * 64 + m * 16 + lk;
                int sl;
                if constexpr (SPR == 4) sl = ((kk * 4 + lg) ^ row ^ (row >> 2)) & 3;
                else                    sl = (kk * 4 + lg) ^ (row & 7);
                af[m] = *(const bf16x8*)&lds[row * RB + sl * 16];
            }
            #pragma unroll
            for (int n = 0; n < 4; ++n) {
                int row = wc * 64 + n * 16 + lk;
                int sl;
                if constexpr (SPR == 4) sl = ((kk * 4 + lg) ^ row ^ (row >> 2)) & 3;
                else                    sl = (kk * 4 + lg) ^ (row & 7);
                bfr[n] = *(const bf16x8*)&lds[128 * RB + row * RB + sl * 16];
            }
            #pragma unroll
            for (int m = 0; m < 4; ++m)
                #pragma unroll
                for (int n = 0; n < 4; ++n)
                    acc[m][n] = __builtin_amdgcn_mfma_f32_16x16x32_bf16(af[m], bfr[n], acc[m][n], 0, 0, 0);
        }
        __syncthreads();
    }

    #pragma unroll
    for (int m = 0; m < 4; ++m) {
        int row = bm + wr * 64 + m * 16 + lg * 4;
        #pragma unroll
        for (int n = 0; n < 4; ++n) {
            int col = bn + wc * 64 + n * 16 + lk;
            #pragma unroll
            for (int r = 0; r < 4; ++r) {
                float v = acc[m][n][r];
                if (EPI >= 1) v += bias[col];
                if (EPI == 2) {
                    float u = v * 0.7978845608f * (1.0f + 0.044715f * v * v);
                    v = v / (1.0f + __expf(-2.0f * u));
                }
                if (OUT_BF)
                    ((unsigned short*)Cout)[(size_t)(row + r) * ldc + col] = f2bf(v);
                else
                    ((float*)Cout)[(size_t)(row + r) * ldc + col] = v;
            }
        }
    }
}

// ---------------------------------------------------------------------------
__global__ __launch_bounds__(256) void cvt_bf16(
    const float* __restrict__ src, unsigned short* __restrict__ dst, int n)
{
    int i = (blockIdx.x * 256 + threadIdx.x) * 4;
    if (i < n) {
        float4 v = *(const float4*)(src + i);
        u16x4 o = { f2bf(v.x), f2bf(v.y), f2bf(v.z), f2bf(v.w) };
        *(u16x4*)(dst + i) = o;
    }
}

// ---------------------------------------------------------------------------
__global__ __launch_bounds__(256) void transpose_cvt(
    const float* __restrict__ src, unsigned short* __restrict__ dst, int R, int Cc)
{
    __shared__ float t[32][33];
    const int bc = blockIdx.x * 32, br = blockIdx.y * 32;
    const int tx = threadIdx.x & 31, ty = threadIdx.x >> 5;
    #pragma unroll
    for (int i = 0; i < 4; ++i)
        t[ty + i * 8][tx] = src[(size_t)(br + ty + i * 8) * Cc + bc + tx];
    __syncthreads();
    #pragma unroll
    for (int i = 0; i < 4; ++i)
        dst[(size_t)(bc + ty + i * 8) * R + br + tx] = f2bf(t[tx][ty + i * 8]);
}

// ---------------------------------------------------------------------------
__global__ __launch_bounds__(256) void drofe_bf(
    const unsigned short* __restrict__ QK, unsigned short* __restrict__ Qo,
    unsigned short* __restrict__ Ko,
    const float* __restrict__ freqband, const float* __restrict__ demo, int N)
{
    const float PI_F = 3.14159265358979323846f;
    int idx = blockIdx.x * 256 + threadIdx.x;
    int col2 = idx & 511;
    int row  = idx >> 9;
    int n = row & (N - 1), b = row >> 10;
    int i  = col2 & 31;
    int ii = (i < 16) ? i : i - 16;
    float fb = (i < 16) ? freqband[n * 2 + 0] : freqband[n * 2 + 1];
    float freq = (1.0f + (float)ii * (4.0f / 15.0f)) * PI_F;
    float ang = fb * freq;
    float cv = cosf(ang), sv = sinf(ang);
    float ca = cv * demo[b * 2 + 0];
    float sg = sv * demo[b * 2 + 1];
    const unsigned* qk = (const unsigned*)(QK + (size_t)row * 2048);
    unsigned qu = qk[col2], ku = qk[512 + col2];
    float qe = bf2f((unsigned short)qu), qo_ = bf2f((unsigned short)(qu >> 16));
    float ke = bf2f((unsigned short)ku), ko_ = bf2f((unsigned short)(ku >> 16));
    const float s8 = 0.125f;
    unsigned qres = (unsigned)f2bf((qe * ca - qo_ * sg) * s8)
                  | ((unsigned)f2bf((qo_ * ca + qe * sg) * s8) << 16);
    unsigned kres = (unsigned)f2bf(ke * ca - ko_ * sg)
                  | ((unsigned)f2bf(ko_ * ca + ke * sg) << 16);
    ((unsigned*)Qo)[(size_t)row * 512 + col2] = qres;
    ((unsigned*)Ko)[(size_t)row * 512 + col2] = kres;
}

// ---------------------------------------------------------------------------
// Flash attention, bf16 in/out, MFMA 16x16x32, fp32 accum. (r10 state)
// ---------------------------------------------------------------------------
__global__ __launch_bounds__(256) void attn_mfma(
    const unsigned short* __restrict__ Q, const unsigned short* __restrict__ K,
    const unsigned short* __restrict__ V, unsigned short* __restrict__ O,
    int B, int H, int N)
{
    __shared__ unsigned short Ks[64 * 64];
    __shared__ unsigned short Vt[64 * 72];
    __shared__ unsigned short Ps[4][16 * 72];

    const int bi = blockIdx.x;
    const int bh = (bi & 7) + 8 * ((bi >> 3) & 15);
    const int q0 = (bi >> 7) * 64;
    const int b = bh >> 4, h = bh & 15;
    const int tid = threadIdx.x;
    const int w = tid >> 6, lane = tid & 63;
    const int lg = lane >> 4, lk = lane & 15;

    bf16x8 qf[2];
    {
        const unsigned short* qrow = Q + (size_t)(b * N + q0 + w * 16 + lk) * 1024 + h * 64;
        qf[0] = *(const bf16x8*)(qrow + lg * 8);
        qf[1] = *(const bf16x8*)(qrow + 32 + lg * 8);
    }

    f32x4 o[4] = {};
    float mrow[4], lrow[4];
    #pragma unroll
    for (int r = 0; r < 4; ++r) { mrow[r] = -INFINITY; lrow[r] = 0.f; }

    for (int t0 = 0; t0 < N; t0 += 64) {
        const size_t kvbase = (size_t)(b * N + t0) * 1024 + h * 64;
        #pragma unroll
        for (int it = 0; it < 2; ++it) {
            int s = it * 256 + tid;
            int row = s >> 3, cb = (s & 7) << 4;
            int dby = cb ^ ((row & 7) << 4);
            GLL16(K + kvbase + (size_t)row * 1024 + (dby >> 1), &Ks[s * 8]);
        }
        {
            int c = tid >> 5, k0 = (tid & 31) * 2;
            const unsigned short* vp = V + kvbase + (size_t)k0 * 1024 + c * 8;
            u16x8 va = *(const u16x8*)vp;
            u16x8 vb = *(const u16x8*)(vp + 1024);
            #pragma unroll
            for (int j = 0; j < 8; ++j) {
                unsigned val = (unsigned)va[j] | ((unsigned)vb[j] << 16);
                *(unsigned*)&Vt[(c * 8 + j) * 72 + k0] = val;
            }
        }
        __syncthreads();

        f32x4 s4[4];
        #pragma unroll
        for (int sub = 0; sub < 4; ++sub) {
            f32x4 acc = {0.f, 0.f, 0.f, 0.f};
            #pragma unroll
            for (int kh = 0; kh < 2; ++kh) {
                int cc = (kh * 64 + lg * 16) ^ ((lk & 7) << 4);
                bf16x8 kf = *(const bf16x8*)&Ks[(sub * 16 + lk) * 64 + (cc >> 1)];
                acc = __builtin_amdgcn_mfma_f32_16x16x32_bf16(qf[kh], kf, acc, 0, 0, 0);
            }
            s4[sub] = acc;
        }

        #pragma unroll
        for (int r = 0; r < 4; ++r) {
            float tm = fmaxf(fmaxf(s4[0][r], s4[1][r]), fmaxf(s4[2][r], s4[3][r]));
            #pragma unroll
            for (int msk = 1; msk < 16; msk <<= 1) tm = fmaxf(tm, __shfl_xor(tm, msk));
            float mn = fmaxf(mrow[r], tm);
            float corr = __expf(mrow[r] - mn);
            mrow[r] = mn;
            float psum = 0.f;
            unsigned short pb[4];
            #pragma unroll
            for (int sub = 0; sub < 4; ++sub) {
                float p = __expf(s4[sub][r] - mn);
                psum += p;
                pb[sub] = (unsigned short)(__float_as_uint(p) >> 16);  // trunc
            }
            #pragma unroll
            for (int msk = 1; msk < 16; msk <<= 1) psum += __shfl_xor(psum, msk);
            lrow[r] = lrow[r] * corr + psum;
            #pragma unroll
            for (int ds = 0; ds < 4; ++ds) o[ds][r] *= corr;
            int q = lg * 4 + r;
            #pragma unroll
            for (int sub = 0; sub < 4; ++sub)
                Ps[w][q * 72 + (((sub * 16 + lk) ^ ((q >> 2) << 3)))] = pb[sub];
        }
        asm volatile("s_waitcnt lgkmcnt(0)" ::: "memory");

        #pragma unroll
        for (int kh = 0; kh < 2; ++kh) {
            bf16x8 pf = *(const bf16x8*)&Ps[w][lk * 72 + ((kh * 32 + lg * 8) ^ ((lk >> 2) << 3))];
            #pragma unroll
            for (int ds = 0; ds < 4; ++ds) {
                bf16x8 vf = *(const bf16x8*)&Vt[(ds * 16 + lk) * 72 + kh * 32 + lg * 8];
                o[ds] = __builtin_amdgcn_mfma_f32_16x16x32_bf16(pf, vf, o[ds], 0, 0, 0);
            }
        }
        __syncthreads();
    }

    #pragma unroll
    for (int ds = 0; ds < 4; ++ds)
        #pragma unroll
        for (int r = 0; r < 4; ++r) {
            int q = lg * 4 + r;
            O[(size_t)(b * N + q0 + w * 16 + q) * 1024 + h * 64 + ds * 16 + lk] =
                f2bf(o[ds][r] / lrow[r]);
        }
}

// ---------------------------------------------------------------------------
__global__ __launch_bounds__(256) void ln_res_kernel(
    const float* __restrict__ x, const float* __restrict__ y,
    const float* __restrict__ gamma, const float* __restrict__ w,
    const float* __restrict__ bia, float* __restrict__ out,
    unsigned short* __restrict__ out_bf, int C)
{
    const int row = blockIdx.x;
    __shared__ float buf[1024];
    __shared__ float red[8];
    const size_t base = (size_t)row * C;
    float s = 0.f, ss = 0.f;
    for (int c = threadIdx.x; c < C; c += 256) {
        float v = x[base + c] + gamma[c] * y[base + c];
        buf[c] = v; s += v; ss += v * v;
    }
    #pragma unroll
    for (int msk = 1; msk < 64; msk <<= 1) { s += __shfl_xor(s, msk); ss += __shfl_xor(ss, msk); }
    int wv = threadIdx.x >> 6, lane = threadIdx.x & 63;
    if (lane == 0) { red[wv * 2] = s; red[wv * 2 + 1] = ss; }
    __syncthreads();
    if (threadIdx.x == 0) {
        float S = 0.f, SS = 0.f;
        #pragma unroll
        for (int i = 0; i < 4; ++i) { S += red[2 * i]; SS += red[2 * i + 1]; }
        red[0] = S; red[1] = SS;
    }
    __syncthreads();
    float mu = red[0] / C;
    float var = red[1] / C - mu * mu;
    float rstd = rsqrtf(var + 1e-5f);
    for (int c = threadIdx.x; c < C; c += 256) {
        float v = (buf[c] - mu) * rstd * w[c] + bia[c];
        out[base + c] = v;
        if (out_bf) out_bf[base + c] = f2bf(v);
    }
}

// ---------------------------------------------------------------------------
extern "C" void kernel_launch(void* const* d_in, const int* in_sizes, int n_in,
                              void* d_out, int out_size, void* d_ws, size_t ws_size,
                              hipStream_t stream)
{
    const float* x      = (const float*)d_in[0];
    const float* demo   = (const float*)d_in[1];
    const float* expl   = (const float*)d_in[2];
    const float* fb     = (const float*)d_in[3];
    const float* w_qkv  = (const float*)d_in[4];
    const float* w_proj = (const float*)d_in[5];
    const float* b_proj = (const float*)d_in[6];
    const float* gamma1 = (const float*)d_in[7];
    const float* gamma2 = (const float*)d_in[8];
    const float* ln1_w  = (const float*)d_in[9];
    const float* ln1_b  = (const float*)d_in[10];
    const float* ln2_w  = (const float*)d_in[11];
    const float* ln2_b  = (const float*)d_in[12];
    const float* w1     = (const float*)d_in[13];
    const float* b1     = (const float*)d_in[14];
    const float* w2     = (const float*)d_in[15];
    const float* b2     = (const float*)d_in[16];
    float* out = (float*)d_out;

    const int B = 8, N = 1024, C = 1024, F = 4096, H = 16;
    const int M = B * N;                        // 8192
    const size_t Mi = 1048576;

    float* ws = (float*)d_ws;
    unsigned short* QKbf = (unsigned short*)ws;              // M x 2048 bf16
    unsigned short* Obf  = (unsigned short*)ws;              // M x 1024 bf16
    float*          H2   = ws;                               // M x 1024 f32
    unsigned short* Qbf  = (unsigned short*)(ws + 8 * Mi);   // M x 1024 bf16
    unsigned short* Kbf  = (unsigned short*)(ws + 12 * Mi);
    unsigned short* Vbf  = (unsigned short*)(ws + 16 * Mi);
    unsigned short* Hid  = (unsigned short*)(ws + 8 * Mi);   // M x 4096 bf16
    unsigned short* Ebf  = (unsigned short*)(ws + 24 * Mi);
    unsigned short* Xbf  = (unsigned short*)(ws + 28 * Mi);
    float*          Pb   = ws + 24 * Mi;                     // M x 1024 f32
    float*          X1   = ws + 32 * Mi;                     // M x 1024 f32
    unsigned short* X1bf = (unsigned short*)(ws + 40 * Mi);
    unsigned short* Wt   = (unsigned short*)(ws + 44 * Mi);
    unsigned short* wqkvT  = Wt;                             // [3072][1024]
    unsigned short* wprojT = Wt + (size_t)3145728;           // [1024][1024]
    unsigned short* w1T    = wprojT + (size_t)1048576;       // [4096][1024]
    unsigned short* w2T    = w1T + (size_t)4194304;          // [1024][4096]

    dim3 blk(256);
    dim3 blk5(512);
    const int MC = M * C;

    hipLaunchKernelGGL(cvt_bf16, dim3(MC / 1024), blk, 0, stream, expl, Ebf, MC);
    hipLaunchKernelGGL(cvt_bf16, dim3(MC / 1024), blk, 0, stream, x, Xbf, MC);
    hipLaunchKernelGGL(transpose_cvt, dim3(96, 32), blk, 0, stream, w_qkv, wqkvT, C, 3 * C);
    hipLaunchKernelGGL(transpose_cvt, dim3(32, 32), blk, 0, stream, w_proj, wprojT, C, C);
    hipLaunchKernelGGL(transpose_cvt, dim3(128, 32), blk, 0, stream, w1, w1T, C, F);
    hipLaunchKernelGGL(transpose_cvt, dim3(32, 128), blk, 0, stream, w2, w2T, F, C);

    // QK projection (explanation) -> bf16 [2ph 256^2]; V projection (x) -> bf16
    hipLaunchKernelGGL((gemm2ph<0,1>), dim3(32 * 8), blk5, 0, stream, Ebf, wqkvT, (const float*)nullptr, (void*)QKbf, M, 2048, C, 2048);
    hipLaunchKernelGGL((gemm97<0,1,32>), dim3(64 * 8), blk, 0, stream, Xbf, wqkvT + (size_t)2048 * 1024, (const float*)nullptr, (void*)Vbf, M, 1024, C, 1024);

    // drofe: bf16 QK -> rotated bf16 Q (scaled), K
    hipLaunchKernelGGL(drofe_bf, dim3(M * 512 / 256), blk, 0, stream, QKbf, Qbf, Kbf, fb, demo, N);

    // attention -> bf16 O
    hipLaunchKernelGGL(attn_mfma, dim3(B * H * (N / 64)), blk, 0, stream, Qbf, Kbf, Vbf, Obf, B, H, N);

    // output projection [BK=32]
    hipLaunchKernelGGL((gemm97<1,0,32>), dim3(64 * 8), blk, 0, stream, Obf, wprojT, b_proj, (void*)Pb, M, 1024, C, 1024);

    // residual + LN1 (f32 + bf16)
    hipLaunchKernelGGL(ln_res_kernel, dim3(M), blk, 0, stream, x, Pb, gamma1, ln1_w, ln1_b, X1, X1bf, C);

    // MLP: MLP1 [2ph 256^2, fast gelu], MLP2 [BK=64, K=4096]
    hipLaunchKernelGGL((gemm2ph<2,1>), dim3(32 * 16), blk5, 0, stream, X1bf, w1T, b1, (void*)Hid, M, F, C, F);
    hipLaunchKernelGGL((gemm97<1,0,64>), dim3(64 * 8), blk, 0, stream, Hid, w2T, b2, (void*)H2, M, 1024, F, 1024);

    // residual + LN2 -> out
    hipLaunchKernelGGL(ln_res_kernel, dim3(M), blk, 0, stream, X1, H2, gamma2, ln2_w, ln2_b, out, (unsigned short*)nullptr, C);
}